// Round 1
// baseline (149.826 us; speedup 1.0000x reference)
//
#include <hip/hip_runtime.h>
#include <math.h>

#define NFRAME 128
#define NJOINT 17
#define NPART 7

// joint -> part: HEAD[0..4]=0, SHOULDER[5,6]=1, ELBOW[7,8]=2, WRIST[9,10]=3,
// HIP[11,12]=4, KNEE[13,14]=5, ANKLE[15,16]=6
__device__ __constant__ int c_part_of[NJOINT] = {
    0, 0, 0, 0, 0,   // head
    1, 1,            // shoulder
    2, 2,            // elbow
    3, 3,            // wrist
    4, 4,            // hip
    5, 5,            // knee
    6, 6             // ankle
};

__global__ __launch_bounds__(NFRAME)
void dividpart_kernel(const float* __restrict__ poses, int* __restrict__ out, int nb) {
    const int b = blockIdx.x;
    const int tid = threadIdx.x;

    __shared__ float sp[NFRAME * NJOINT];   // 2176 floats = 8.5 KB
    __shared__ float wmax[2][NPART], wmin[2][NPART];
    __shared__ float pmaxs[NPART], pmins[NPART];

    // Stage this batch's (128,17) f32 slice into LDS with coalesced float4 loads.
    // Slice start byte offset = (3b+1)*8704, and 8704 % 16 == 0, so float4 is aligned.
    const float4* src = (const float4*)(poses + ((size_t)b * 3 + 1) * (size_t)(NFRAME * NJOINT));
    float4* dst = (float4*)sp;
    #pragma unroll
    for (int i = tid; i < (NFRAME * NJOINT) / 4; i += NFRAME) {
        dst[i] = src[i];
    }
    __syncthreads();

    // One thread per frame.
    const float* row = sp + tid * NJOINT;
    const float p0 = row[0];
    // mean over shoulders of (p - p0): ((p5-p0)+(p6-p0))/2  (exact /2)
    const float ratio = ((row[5] - p0) + (row[6] - p0)) * 0.5f;

    // IEEE division to match numpy bit-for-bit (no -ffast-math, no reciprocal).
    float v[NJOINT];
    #pragma unroll
    for (int j = 0; j < NJOINT; j++) {
        v[j] = (row[j] - p0) / ratio;
    }
    float rowmin = v[0];
    #pragma unroll
    for (int j = 1; j < NJOINT; j++) rowmin = fminf(rowmin, v[j]);

    float fmx[NPART], fmn[NPART];
    #pragma unroll
    for (int p = 0; p < NPART; p++) { fmx[p] = -__builtin_inff(); fmn[p] = __builtin_inff(); }
    #pragma unroll
    for (int j = 0; j < NJOINT; j++) {
        const float a = v[j] - rowmin;      // aligned value; row minimum maps to exactly 0
        const int p = c_part_of[j];
        fmx[p] = fmaxf(fmx[p], a);
        fmn[p] = fminf(fmn[p], a);
    }

    // Wave(64)-level butterfly reduction of the 14 values.
    #pragma unroll
    for (int off = 32; off > 0; off >>= 1) {
        #pragma unroll
        for (int p = 0; p < NPART; p++) {
            fmx[p] = fmaxf(fmx[p], __shfl_xor(fmx[p], off));
            fmn[p] = fminf(fmn[p], __shfl_xor(fmn[p], off));
        }
    }
    const int wv = tid >> 6;                 // wave id: 0 or 1
    if ((tid & 63) == 0) {
        #pragma unroll
        for (int p = 0; p < NPART; p++) { wmax[wv][p] = fmx[p]; wmin[wv][p] = fmn[p]; }
    }
    __syncthreads();

    if (tid < NPART) {
        pmaxs[tid] = fmaxf(wmax[0][tid], wmax[1][tid]);
        pmins[tid] = fminf(wmin[0][tid], wmin[1][tid]);
    }
    __syncthreads();

    if (tid < NPART) {
        // Parts cover all 17 joints, so bottom/top are just part-wise max/min.
        float bottom = pmaxs[0], top = pmins[0];
        #pragma unroll
        for (int p = 1; p < NPART; p++) {
            bottom = fmaxf(bottom, pmaxs[p]);
            top = fminf(top, pmins[p]);
        }
        const float denom = bottom - top;
        // Match reference op order: ((x - top) / denom) * 64
        const float ma_f = ceilf((pmaxs[tid] - top) / denom * 64.0f);
        const float mi_f = floorf((pmins[tid] - top) / denom * 64.0f);
        int ma = (int)ma_f;
        int mi = (int)mi_f;
        const int hi = (tid + 1) * 9;
        const int lo = tid * 9;
        if (ma <= mi)      { ma = hi; mi = lo; }
        if (ma - mi > 30)  { ma = hi; mi = lo; }
        out[tid * nb + b]              = ma;   // ma: shape (7, nb)
        out[NPART * nb + tid * nb + b] = mi;   // mi: shape (7, nb)
    }
}

extern "C" void kernel_launch(void* const* d_in, const int* in_sizes, int n_in,
                              void* d_out, int out_size, void* d_ws, size_t ws_size,
                              hipStream_t stream) {
    const float* poses = (const float*)d_in[0];
    int* out = (int*)d_out;
    const int nb = in_sizes[0] / (3 * NFRAME * NJOINT);   // 4096
    dividpart_kernel<<<nb, NFRAME, 0, stream>>>(poses, out, nb);
}

// Round 2
// 144.011 us; speedup vs baseline: 1.0404x; 1.0404x over previous
//
#include <hip/hip_runtime.h>
#include <math.h>

#define NFRAME 128
#define NJOINT 17
#define NPART 7

__global__ __launch_bounds__(64)
void dividpart_kernel(const float* __restrict__ poses, int* __restrict__ out, int nb) {
    const int b = blockIdx.x;
    const int tid = threadIdx.x;   // 0..63, single wave

    __shared__ float sp[NFRAME * NJOINT];   // 2176 floats = 8.5 KB

    // Stage this batch's (128,17) f32 slice into LDS with coalesced float4 loads.
    // Slice start byte offset = (3b+1)*8704, 8704 % 16 == 0 -> float4 aligned.
    const float4* src = (const float4*)(poses + ((size_t)b * 3 + 1) * (size_t)(NFRAME * NJOINT));
    float4* dst = (float4*)sp;
    for (int i = tid; i < (NFRAME * NJOINT) / 4; i += 64) dst[i] = src[i];
    __syncthreads();   // single-wave block: compiles to a waitcnt, barrier is trivial

    // joint -> part (folded at compile time by full unroll)
    const int part_of[NJOINT] = {0,0,0,0,0, 1,1, 2,2, 3,3, 4,4, 5,5, 6,6};

    float fmx[NPART], fmn[NPART];
    #pragma unroll
    for (int p = 0; p < NPART; p++) { fmx[p] = -__builtin_inff(); fmn[p] = __builtin_inff(); }

    // Each lane handles 2 frames: tid and tid+64.
    #pragma unroll
    for (int f = 0; f < 2; f++) {
        const float* row = sp + (tid + f * 64) * NJOINT;
        const float p0 = row[0];
        // mean over shoulders of (p - p0): ((p5-p0)+(p6-p0))/2 (exact /2)
        const float ratio = ((row[5] - p0) + (row[6] - p0)) * 0.5f;

        // IEEE division to match numpy bit-for-bit.
        float v[NJOINT];
        #pragma unroll
        for (int j = 0; j < NJOINT; j++) v[j] = (row[j] - p0) / ratio;

        float rowmin = v[0];
        #pragma unroll
        for (int j = 1; j < NJOINT; j++) rowmin = fminf(rowmin, v[j]);

        #pragma unroll
        for (int j = 0; j < NJOINT; j++) {
            const float a = v[j] - rowmin;   // row minimum maps to exactly 0
            const int p = part_of[j];        // compile-time constant after unroll
            fmx[p] = fmaxf(fmx[p], a);
            fmn[p] = fminf(fmn[p], a);
        }
    }

    // In-wave butterfly reduction across 64 lanes; afterwards ALL lanes hold the result.
    #pragma unroll
    for (int off = 32; off > 0; off >>= 1) {
        #pragma unroll
        for (int p = 0; p < NPART; p++) {
            fmx[p] = fmaxf(fmx[p], __shfl_xor(fmx[p], off));
            fmn[p] = fminf(fmn[p], __shfl_xor(fmn[p], off));
        }
    }

    if (tid < NPART) {
        // bottom/top: parts cover all joints, so global max/min = part-wise max/min.
        float bottom = fmx[0], top = fmn[0];
        #pragma unroll
        for (int p = 1; p < NPART; p++) {
            bottom = fmaxf(bottom, fmx[p]);
            top = fminf(top, fmn[p]);
        }
        const float denom = bottom - top;

        // Select this lane's part values without dynamic register indexing.
        float pm = fmx[0], pn = fmn[0];
        #pragma unroll
        for (int p = 1; p < NPART; p++) {
            if (tid == p) { pm = fmx[p]; pn = fmn[p]; }
        }

        // Match reference op order: ((x - top) / denom) * 64
        const float ma_f = ceilf((pm - top) / denom * 64.0f);
        const float mi_f = floorf((pn - top) / denom * 64.0f);
        int ma = (int)ma_f;
        int mi = (int)mi_f;
        const int hi = (tid + 1) * 9;
        const int lo = tid * 9;
        if (ma <= mi)     { ma = hi; mi = lo; }
        if (ma - mi > 30) { ma = hi; mi = lo; }
        out[tid * nb + b]              = ma;   // ma: (7, nb)
        out[NPART * nb + tid * nb + b] = mi;   // mi: (7, nb)
    }
}

extern "C" void kernel_launch(void* const* d_in, const int* in_sizes, int n_in,
                              void* d_out, int out_size, void* d_ws, size_t ws_size,
                              hipStream_t stream) {
    const float* poses = (const float*)d_in[0];
    int* out = (int*)d_out;
    const int nb = in_sizes[0] / (3 * NFRAME * NJOINT);   // 4096
    dividpart_kernel<<<nb, 64, 0, stream>>>(poses, out, nb);
}

// Round 3
// 140.010 us; speedup vs baseline: 1.0701x; 1.0286x over previous
//
#include <hip/hip_runtime.h>
#include <math.h>

#define NFRAME 128
#define NJOINT 17
#define NPART 7

__global__ __launch_bounds__(64)
void dividpart_kernel(const float* __restrict__ poses, int* __restrict__ out, int nb) {
    const int b = blockIdx.x;
    const int tid = threadIdx.x;   // 0..63, single wave, no LDS

    // Batch slice: poses[b, 1, :, :] = 128 rows x 17 floats, contiguous 8704 B.
    const float* base = poses + ((size_t)b * 3 + 1) * (size_t)(NFRAME * NJOINT);

    // joint -> part (folded at compile time by full unroll)
    const int part_of[NJOINT] = {0,0,0,0,0, 1,1, 2,2, 3,3, 4,4, 5,5, 6,6};

    float fmx[NPART], fmn[NPART];
    #pragma unroll
    for (int p = 0; p < NPART; p++) { fmx[p] = -__builtin_inff(); fmn[p] = __builtin_inff(); }

    // Each lane handles 2 frames: tid and tid+64. Row = 17 contiguous floats
    // (68 B); a wave's 64 rows span one contiguous 4352 B region, so direct
    // float4 loads (dword-aligned) touch each 128 B line exactly once.
    #pragma unroll
    for (int f = 0; f < 2; f++) {
        const float* row = base + (size_t)(tid + f * 64) * NJOINT;

        float v[NJOINT];
        {
            // 4x float4 + 1 scalar; row is 4B-aligned (68 % 16 == 4 is fine).
            const float4 q0 = *(const float4*)(row + 0);
            const float4 q1 = *(const float4*)(row + 4);
            const float4 q2 = *(const float4*)(row + 8);
            const float4 q3 = *(const float4*)(row + 12);
            v[0]=q0.x; v[1]=q0.y; v[2]=q0.z; v[3]=q0.w;
            v[4]=q1.x; v[5]=q1.y; v[6]=q1.z; v[7]=q1.w;
            v[8]=q2.x; v[9]=q2.y; v[10]=q2.z; v[11]=q2.w;
            v[12]=q3.x; v[13]=q3.y; v[14]=q3.z; v[15]=q3.w;
            v[16]=row[16];
        }

        const float p0 = v[0];
        // mean over shoulders of (p - p0): ((p5-p0)+(p6-p0))/2 (exact /2)
        const float ratio = ((v[5] - p0) + (v[6] - p0)) * 0.5f;

        // IEEE division to match numpy bit-for-bit.
        #pragma unroll
        for (int j = 0; j < NJOINT; j++) v[j] = (v[j] - p0) / ratio;

        float rowmin = v[0];
        #pragma unroll
        for (int j = 1; j < NJOINT; j++) rowmin = fminf(rowmin, v[j]);

        #pragma unroll
        for (int j = 0; j < NJOINT; j++) {
            const float a = v[j] - rowmin;   // row minimum maps to exactly 0
            const int p = part_of[j];        // compile-time constant after unroll
            fmx[p] = fmaxf(fmx[p], a);
            fmn[p] = fminf(fmn[p], a);
        }
    }

    // In-wave butterfly reduction across 64 lanes; afterwards ALL lanes hold the result.
    #pragma unroll
    for (int off = 32; off > 0; off >>= 1) {
        #pragma unroll
        for (int p = 0; p < NPART; p++) {
            fmx[p] = fmaxf(fmx[p], __shfl_xor(fmx[p], off));
            fmn[p] = fminf(fmn[p], __shfl_xor(fmn[p], off));
        }
    }

    if (tid < NPART) {
        // bottom/top: parts cover all joints, so global max/min = part-wise max/min.
        float bottom = fmx[0], top = fmn[0];
        #pragma unroll
        for (int p = 1; p < NPART; p++) {
            bottom = fmaxf(bottom, fmx[p]);
            top = fminf(top, fmn[p]);
        }
        const float denom = bottom - top;

        // Select this lane's part values without dynamic register indexing.
        float pm = fmx[0], pn = fmn[0];
        #pragma unroll
        for (int p = 1; p < NPART; p++) {
            if (tid == p) { pm = fmx[p]; pn = fmn[p]; }
        }

        // Match reference op order: ((x - top) / denom) * 64
        const float ma_f = ceilf((pm - top) / denom * 64.0f);
        const float mi_f = floorf((pn - top) / denom * 64.0f);
        int ma = (int)ma_f;
        int mi = (int)mi_f;
        const int hi = (tid + 1) * 9;
        const int lo = tid * 9;
        if (ma <= mi)     { ma = hi; mi = lo; }
        if (ma - mi > 30) { ma = hi; mi = lo; }
        out[tid * nb + b]              = ma;   // ma: (7, nb)
        out[NPART * nb + tid * nb + b] = mi;   // mi: (7, nb)
    }
}

extern "C" void kernel_launch(void* const* d_in, const int* in_sizes, int n_in,
                              void* d_out, int out_size, void* d_ws, size_t ws_size,
                              hipStream_t stream) {
    const float* poses = (const float*)d_in[0];
    int* out = (int*)d_out;
    const int nb = in_sizes[0] / (3 * NFRAME * NJOINT);   // 4096
    dividpart_kernel<<<nb, 64, 0, stream>>>(poses, out, nb);
}